// Round 8
// baseline (2109.339 us; speedup 1.0000x reference)
//
#include <hip/hip_runtime.h>
#include <math.h>

// ============================================================================
// Persistent FFT ISTA solver, radix-8, pair-packed, REGISTER-STATE edition.
//
// Math per signal (identical recurrence to r1..r7, all PASSED):
//   u_{t+1} = u_t - 0.05*(I-P)*clamp20(u_t),  u_0 = 100*DCT(scatter(x[idxs]))
//   P*h = DCT2(mask(IDCT(h))),  out = 0.01*IDCT(u_99 - 0.05*clamp20(u_99)).
// Pair packing (r7, verified): signals (2p, 2p+1) share one complex FFT;
//   V-build uses P = X0k+X1N, Q = X0N-X1k; DCT2 split via conj-symmetry.
//
// r7 -> r8: ISTA state gp moves from LDS (16 KB) into registers gr0..gr7
// (8 cf/thread, k = t+256b; statically indexed — rule #20). LDS halves to
// 16.7 KB -> 4 resident blocks/CU (16 waves, was 12); PPB=1, grid 1536.
// Head now stages h through the dead wk buffer (own-h store, barrier,
// partner read of h[2048-k] from thread 256-t, barrier, V overwrite) —
// +2 barriers/iter, -32 LDS cf-ops/iter (tail gp r/w gone).
//
// Kept (r6-verified spill fix, FETCH 23GB -> 12MB): only 15 scalar
// loop-invariants, re-anchored per iteration with empty asm; twiddle powers
// rebuilt per stage by chained cmul. DO NOT REMOVE.
//
// FFT: 2048 = 8*8*8*4, 256 threads, 8 cf/thread.
//   Slot p = 256b' + 32c' + 4d' + e' holds Y[m], m = b' + 8c' + 64d' + 512e'.
//   LDS XOR-swizzle swz(p) = p ^ (((p>>5)&7)<<2); note swz(t+256j) =
//   swz(t)+256j (bits 5-7 unaffected by +256j), so A0j slots ARE swz(k).
// ============================================================================

#define PIF 3.14159265358979323846f
#define C0F 0.022097086912079608f      // sqrt(1/2048)
#define TWOC0 0.044194173824159216f    // 2*sqrt(1/2048)
#define CNF 0.03125f                   // sqrt(2/2048)

typedef float2 cf;

__device__ __forceinline__ int load_idx(const int* p, int j) {
    return (p[1] == 0) ? p[2 * j] : p[j];   // int64 (lo,0) pairs or int32
}
__device__ __forceinline__ int pinv(int m) {   // frequency -> slot
    return ((m & 7) << 8) | (((m >> 3) & 7) << 5) | (((m >> 6) & 7) << 2) | ((m >> 9) & 3);
}
__device__ __forceinline__ int permf(int p) {  // slot -> frequency
    return (p >> 8) | (((p >> 5) & 7) << 3) | (((p >> 2) & 7) << 6) | ((p & 3) << 9);
}
__device__ __forceinline__ float clamp20(float g) {
    return fminf(fmaxf(20.f * g, -1.f), 1.f);
}
__device__ __forceinline__ cf cadd(cf a, cf b) { return make_float2(a.x + b.x, a.y + b.y); }
__device__ __forceinline__ cf csub(cf a, cf b) { return make_float2(a.x - b.x, a.y - b.y); }
__device__ __forceinline__ cf cmul(cf a, cf b) {
    return make_float2(a.x * b.x - a.y * b.y, a.x * b.y + a.y * b.x);
}
__device__ __forceinline__ cf cmulc(cf a, cf b) {   // a * conj(b)
    return make_float2(a.x * b.x + a.y * b.y, a.y * b.x - a.x * b.y);
}
template <int S> __device__ __forceinline__ cf imul(cf z) {  // (S*i)*z
    return (S > 0) ? make_float2(-z.y, z.x) : make_float2(z.y, -z.x);
}

template <int S>
__device__ __forceinline__ void dft8r(cf& v0, cf& v1, cf& v2, cf& v3,
                                      cf& v4, cf& v5, cf& v6, cf& v7) {
    const float R2 = 0.70710678118654752f;
    cf A0 = cadd(v0, v4), D0 = csub(v0, v4);
    cf A1 = cadd(v1, v5), D1 = csub(v1, v5);
    cf A2 = cadd(v2, v6), D2 = csub(v2, v6);
    cf A3 = cadd(v3, v7), D3 = csub(v3, v7);
    const cf w8  = make_float2(R2, (S > 0) ? R2 : -R2);
    const cf w83 = make_float2(-R2, (S > 0) ? R2 : -R2);
    D1 = cmul(D1, w8);
    D2 = imul<S>(D2);
    D3 = cmul(D3, w83);
    cf E0 = cadd(A0, A2), E1 = csub(A0, A2);
    cf O0 = cadd(A1, A3), O1 = imul<S>(csub(A1, A3));
    cf F0 = cadd(D0, D2), F1 = csub(D0, D2);
    cf P0 = cadd(D1, D3), P1 = imul<S>(csub(D1, D3));
    v0 = cadd(E0, O0); v2 = cadd(E1, O1);
    v4 = csub(E0, O0); v6 = csub(E1, O1);
    v1 = cadd(F0, P0); v3 = cadd(F1, P1);
    v5 = csub(F0, P0); v7 = csub(F1, P1);
}

template <int S>
__device__ __forceinline__ void dft4r(cf& v0, cf& v1, cf& v2, cf& v3) {
    cf E0 = cadd(v0, v2), E1 = csub(v0, v2);
    cf O0 = cadd(v1, v3), O1 = imul<S>(csub(v1, v3));
    v0 = cadd(E0, O0); v1 = cadd(E1, O1);
    v2 = csub(E0, O0); v3 = csub(E1, O1);
}

// cos/sin(pi*b/16) literals, b = 0..7
#define CRL0 1.0f
#define CRL1 0.980785280403230449f
#define CRL2 0.923879532511286756f
#define CRL3 0.831469612302545237f
#define CRL4 0.707106781186547524f
#define CRL5 0.555570233019602225f
#define CRL6 0.382683432365089772f
#define CRL7 0.195090322016128268f
#define SRL0 0.0f
#define SRL1 CRL7
#define SRL2 CRL6
#define SRL3 CRL5
#define SRL4 CRL4
#define SRL5 CRL3
#define SRL6 CRL2
#define SRL7 CRL1

#define SWZ(p) ((p) ^ ((((p) >> 5) & 7) << 2))
#define A0j(j) (tswv + 256 * (j))
#define A1j(j) ((s1bv ^ ((j) << 2)) + 32 * (j) + 256 * t5v)
#define A2j(j) (s2kv + 4 * ((j) ^ s2cv) + 32 * s2cv + 256 * t5v)

#define LOAD8(A) cf v0 = wk[A(0)], v1 = wk[A(1)], v2 = wk[A(2)], v3 = wk[A(3)], \
                    v4 = wk[A(4)], v5 = wk[A(5)], v6 = wk[A(6)], v7 = wk[A(7)]
#define STORE8(A) wk[A(0)] = v0; wk[A(1)] = v1; wk[A(2)] = v2; wk[A(3)] = v3; \
                  wk[A(4)] = v4; wk[A(5)] = v5; wk[A(6)] = v6; wk[A(7)] = v7

// chained twiddle powers from the generator (PX,PY): w walks P^1..P^7
#define TWCHAINF(PX, PY) { const cf P_ = make_float2((PX), (PY)); cf w_ = P_; \
    v1 = cmul(v1, w_); w_ = cmul(w_, P_); v2 = cmul(v2, w_); w_ = cmul(w_, P_); \
    v3 = cmul(v3, w_); w_ = cmul(w_, P_); v4 = cmul(v4, w_); w_ = cmul(w_, P_); \
    v5 = cmul(v5, w_); w_ = cmul(w_, P_); v6 = cmul(v6, w_); w_ = cmul(w_, P_); \
    v7 = cmul(v7, w_); }
#define TWCHAINB(PX, PY) { const cf P_ = make_float2((PX), (PY)); cf w_ = P_; \
    v1 = cmulc(v1, w_); w_ = cmul(w_, P_); v2 = cmulc(v2, w_); w_ = cmul(w_, P_); \
    v3 = cmulc(v3, w_); w_ = cmul(w_, P_); v4 = cmulc(v4, w_); w_ = cmul(w_, P_); \
    v5 = cmulc(v5, w_); w_ = cmul(w_, P_); v6 = cmulc(v6, w_); w_ = cmul(w_, P_); \
    v7 = cmulc(v7, w_); }

#define DIFMID(A, PX, PY) { LOAD8(A); dft8r<1>(v0, v1, v2, v3, v4, v5, v6, v7); \
                            TWCHAINF(PX, PY); STORE8(A); }
#define DITMID(A, PX, PY) { LOAD8(A); TWCHAINB(PX, PY); \
                            dft8r<-1>(v0, v1, v2, v3, v4, v5, v6, v7); STORE8(A); }

// --- head phase 1: compute h for own k (both signals), stage into wk ---
#define HCOMP(b, hb) { \
    float h0_, h1_; \
    if (fin) { h0_ = gr##b.x - 0.05f * clamp20(gr##b.x); \
               h1_ = gr##b.y - 0.05f * clamp20(gr##b.y); } \
    else     { h0_ = clamp20(gr##b.x); h1_ = clamp20(gr##b.y); } \
    hb = make_float2(h0_, h1_); \
    wk[A0j(b)] = hb; }

// --- head phase 2: partner h at kN = 2048-k (thread 256-t's slot) ---
#define PREAD(b, pn) { \
    const int kN_ = (2048 - (ta + 256 * (b))) & 2047; \
    pn = wk[SWZ(kN_)]; }

// --- head phase 3: packed V (r7-verified): P = X0k+X1N, Q = X0N-X1k ---
#define MKV2(b, hb, pn, vo) { \
    const bool kz_ = ((b) == 0) && (ta == 0); \
    const float s_ = kz_ ? TWOC0 : CNF; \
    const float X0k_ = s_ * hb.x, X1k_ = s_ * hb.y; \
    const float X0N_ = kz_ ? 0.f : CNF * pn.x; \
    const float X1N_ = kz_ ? 0.f : CNF * pn.y; \
    const float Pp_ = X0k_ + X1N_, Qq_ = X0N_ - X1k_; \
    const float cc_ = c0a * (CRL##b) - s0a * (SRL##b); \
    const float ss_ = s0a * (CRL##b) + c0a * (SRL##b); \
    vo = make_float2(0.5f * (Pp_ * cc_ + Qq_ * ss_), 0.5f * (Pp_ * ss_ - Qq_ * cc_)); }

#define HEADP(finv) { \
    const bool fin = (finv); \
    cf h0, h1, h2, h3, h4, h5, h6, h7; \
    HCOMP(0, h0) HCOMP(1, h1) HCOMP(2, h2) HCOMP(3, h3) \
    HCOMP(4, h4) HCOMP(5, h5) HCOMP(6, h6) HCOMP(7, h7) \
    __syncthreads(); \
    cf p0, p1, p2, p3, p4, p5, p6, p7; \
    PREAD(0, p0) PREAD(1, p1) PREAD(2, p2) PREAD(3, p3) \
    PREAD(4, p4) PREAD(5, p5) PREAD(6, p6) PREAD(7, p7) \
    __syncthreads(); \
    cf v0, v1, v2, v3, v4, v5, v6, v7; \
    MKV2(0, h0, p0, v0) MKV2(1, h1, p1, v1) MKV2(2, h2, p2, v2) MKV2(3, h3, p3, v3) \
    MKV2(4, h4, p4, v4) MKV2(5, h5, p5, v5) MKV2(6, h6, p6, v6) MKV2(7, h7, p7, v7) \
    dft8r<1>(v0, v1, v2, v3, v4, v5, v6, v7); \
    TWCHAINF(cww, sww); STORE8(A0j); }

// Tail per-k: conj-symmetry split, DCT-II epilogue, REGISTER g update
#define TPJ(j) { \
    const int k_ = ta + 256 * (j); \
    const int kp_ = (2048 - k_) & 2047; \
    const cf pz_ = wk[SWZ(kp_)]; \
    const float cc_ = c0a * (CRL##j) - s0a * (SRL##j); \
    const float ss_ = s0a * (CRL##j) + c0a * (SRL##j); \
    const float C0_ = 0.5f * (cc_ * (v##j.x + pz_.x) + ss_ * (v##j.y - pz_.y)); \
    const float C1_ = 0.5f * (cc_ * (v##j.y + pz_.y) + ss_ * (pz_.x - v##j.x)); \
    const float ck_ = ((((j) == 0) && (ta == 0)) ? C0F : CNF); \
    const float u0_ = ck_ * C0_, u1_ = ck_ * C1_; \
    if (init) { gr##j = make_float2(u0_, u1_); } \
    else { gr##j = make_float2(gr##j.x + 0.05f * (u0_ - clamp20(gr##j.x)), \
                               gr##j.y + 0.05f * (u1_ - clamp20(gr##j.y))); } }

#define TAILP(initv) { \
    const bool init = (initv); \
    LOAD8(A0j); TWCHAINB(cww, sww); dft8r<-1>(v0, v1, v2, v3, v4, v5, v6, v7); \
    STORE8(A0j); \
    __syncthreads(); \
    TPJ(0) TPJ(1) TPJ(2) TPJ(3) TPJ(4) TPJ(5) TPJ(6) TPJ(7) }

// S3 + mask + T0 in registers; mask multiplies BOTH components (packed pair)
#define QUADMASK(q) { \
    const int pb_ = 8 * ta + 4 * (q); \
    const int a_ = SWZ(pb_); \
    float4 lo_ = *(const float4*)(&wk[a_]); \
    float4 hi_ = *(const float4*)(&wk[a_ + 2]); \
    cf u0 = make_float2(lo_.x, lo_.y), u1 = make_float2(lo_.z, lo_.w); \
    cf u2 = make_float2(hi_.x, hi_.y), u3 = make_float2(hi_.z, hi_.w); \
    dft4r<1>(u0, u1, u2, u3); \
    { const float k0_ = (float)((mskv >> (4 * (q) + 0)) & 1u); u0.x *= k0_; u0.y *= k0_; } \
    { const float k1_ = (float)((mskv >> (4 * (q) + 1)) & 1u); u1.x *= k1_; u1.y *= k1_; } \
    { const float k2_ = (float)((mskv >> (4 * (q) + 2)) & 1u); u2.x *= k2_; u2.y *= k2_; } \
    { const float k3_ = (float)((mskv >> (4 * (q) + 3)) & 1u); u3.x *= k3_; u3.y *= k3_; } \
    dft4r<-1>(u0, u1, u2, u3); \
    *(float4*)(&wk[a_])     = make_float4(u0.x, u0.y, u1.x, u1.y); \
    *(float4*)(&wk[a_ + 2]) = make_float4(u2.x, u2.y, u3.x, u3.y); }

#define QUADT0(q) { \
    const int pb_ = 8 * ta + 4 * (q); \
    const int a_ = SWZ(pb_); \
    float4 lo_ = *(const float4*)(&wk[a_]); \
    float4 hi_ = *(const float4*)(&wk[a_ + 2]); \
    cf u0 = make_float2(lo_.x, lo_.y), u1 = make_float2(lo_.z, lo_.w); \
    cf u2 = make_float2(hi_.x, hi_.y), u3 = make_float2(hi_.z, hi_.w); \
    dft4r<-1>(u0, u1, u2, u3); \
    *(float4*)(&wk[a_])     = make_float4(u0.x, u0.y, u1.x, u1.y); \
    *(float4*)(&wk[a_ + 2]) = make_float4(u2.x, u2.y, u3.x, u3.y); }

// THE r6-verified spill fix: re-anchor the 15 scalar invariants so LICM can't
// hoist derived values (FETCH 23GB -> 12MB when applied). Do not remove.
#define ANCHOR() asm volatile("" \
    : "+v"(cww), "+v"(sww), "+v"(coo), "+v"(soo), "+v"(cll), "+v"(sll), \
      "+v"(c0a), "+v"(s0a), "+v"(ta), "+v"(tswv), "+v"(s1bv), "+v"(t5v), \
      "+v"(s2kv), "+v"(s2cv), "+v"(mskv))

__global__ __launch_bounds__(256) void ista_fft_kernel(
    const float* __restrict__ x, const int* __restrict__ idxs,
    float* __restrict__ out)
{
    __shared__ __align__(16) cf wk[2048];   // 16 KB, swizzled slot space
    __shared__ unsigned mbm[64];            // ~16.7 KB total -> 4 blocks/CU

    const int t = threadIdx.x;
    int ta   = t;
    int t5v  = t >> 5;
    int s1bv = t & 31;
    int s2kv = t & 3;
    int s2cv = (t >> 2) & 7;
    int tswv = SWZ(t);

    if (t < 64) mbm[t] = 0u;
    __syncthreads();

    const int mi0 = load_idx(idxs, t), mi1 = load_idx(idxs, t + 256);
    const int yd0 = (mi0 & 1) ? (2047 - (mi0 >> 1)) : (mi0 >> 1);
    const int yd1 = (mi1 & 1) ? (2047 - (mi1 >> 1)) : (mi1 >> 1);
    const int pm0 = pinv(yd0), pm1 = pinv(yd1);
    atomicOr(&mbm[pm0 >> 5], 1u << (pm0 & 31));
    atomicOr(&mbm[pm1 >> 5], 1u << (pm1 & 31));
    const int sl0 = SWZ(pm0), sl1 = SWZ(pm1);
    __syncthreads();
    unsigned mskv = (mbm[t >> 2] >> ((t & 3) * 8)) & 0xffu;

    // the ONLY trig state: generators + half-angle pair (8 floats)
    float s0a, c0a; sincosf(PIF * (float)t * (1.f / 4096.f), &s0a, &c0a);
    float sww, cww; sincosf(2.f * PIF * (float)t    * (1.f / 2048.f), &sww, &cww);
    float soo, coo; sincosf(2.f * PIF * (float)s1bv * (1.f / 256.f),  &soo, &coo);
    float sll, cll; sincosf(2.f * PIF * (float)s2kv * (1.f / 32.f),   &sll, &cll);

    // ISTA state in registers: gr_b = (u_s[k], u_{s+1}[k]), k = t + 256b
    cf gr0, gr1, gr2, gr3, gr4, gr5, gr6, gr7;

    const int r0 = 2 * blockIdx.x, r1 = r0 + 1;   // one pair per block
    ANCHOR();

    // ---- init: wk = scatter(100*(x0 + i*x1)) in swizzled slot space ----
#pragma unroll
    for (int j = 0; j < 8; ++j) wk[t + 256 * j] = make_float2(0.f, 0.f);
    __syncthreads();
    wk[sl0] = make_float2(100.f * x[(size_t)r0 * 2048 + mi0],
                          100.f * x[(size_t)r1 * 2048 + mi0]);
    wk[sl1] = make_float2(100.f * x[(size_t)r0 * 2048 + mi1],
                          100.f * x[(size_t)r1 * 2048 + mi1]);
    __syncthreads();
    QUADT0(0) QUADT0(1)                       // plain T0 (input pre-masked)
    __syncthreads();
    DITMID(A2j, cll, sll); __syncthreads();   // T1
    DITMID(A1j, coo, soo); __syncthreads();   // T2
    TAILP(true);           __syncthreads();   // gr = (u0_s, u0_{s+1})

    // ---- 99 iterations (per pair) ----
#pragma unroll 1
    for (int it = 0; it < 99; ++it) {
        ANCHOR();
        HEADP(false);          __syncthreads();   // S0 (h-exchange + V + dft8)
        DIFMID(A1j, coo, soo); __syncthreads();   // S1
        DIFMID(A2j, cll, sll); __syncthreads();   // S2
        QUADMASK(0) QUADMASK(1)                   // S3 + mask + T0 in regs
        __syncthreads();
        DITMID(A2j, cll, sll); __syncthreads();   // T1
        DITMID(A1j, coo, soo); __syncthreads();   // T2
        TAILP(false);          __syncthreads();   // split + gr update
    }

    // ---- final: out_s = 0.01*Re, out_{s+1} = 0.01*Im of IDCT(F') ----
    ANCHOR();
    HEADP(true);           __syncthreads();
    DIFMID(A1j, coo, soo); __syncthreads();
    DIFMID(A2j, cll, sll); __syncthreads();
    {   // S3 into regs (both quads), then scatter to x-order through wk
        cf e0, e1, e2, e3, e4, e5, e6, e7;
        {
            const int a_ = SWZ(8 * ta);
            float4 lo_ = *(const float4*)(&wk[a_]);
            float4 hi_ = *(const float4*)(&wk[a_ + 2]);
            e0 = make_float2(lo_.x, lo_.y); e1 = make_float2(lo_.z, lo_.w);
            e2 = make_float2(hi_.x, hi_.y); e3 = make_float2(hi_.z, hi_.w);
            dft4r<1>(e0, e1, e2, e3);
        }
        {
            const int a_ = SWZ(8 * ta + 4);
            float4 lo_ = *(const float4*)(&wk[a_]);
            float4 hi_ = *(const float4*)(&wk[a_ + 2]);
            e4 = make_float2(lo_.x, lo_.y); e5 = make_float2(lo_.z, lo_.w);
            e6 = make_float2(hi_.x, hi_.y); e7 = make_float2(hi_.z, hi_.w);
            dft4r<1>(e4, e5, e6, e7);
        }
        __syncthreads();   // all quad reads done before wk is repurposed
#define FSC(e, off) { \
        const int m_ = permf(8 * ta + (off)); \
        const int i_ = (m_ < 1024) ? (m_ << 1) : (4095 - (m_ << 1)); \
        wk[i_] = make_float2(0.01f * e.x, 0.01f * e.y); }
        FSC(e0, 0) FSC(e1, 1) FSC(e2, 2) FSC(e3, 3)
        FSC(e4, 4) FSC(e5, 5) FSC(e6, 6) FSC(e7, 7)
#undef FSC
        __syncthreads();
#pragma unroll
        for (int j = 0; j < 8; ++j) {
            const cf o_ = wk[t + 256 * j];
            out[(size_t)r0 * 2048 + t + 256 * j] = o_.x;
            out[(size_t)r1 * 2048 + t + 256 * j] = o_.y;
        }
    }
}

extern "C" void kernel_launch(void* const* d_in, const int* in_sizes, int n_in,
                              void* d_out, int out_size, void* d_ws, size_t ws_size,
                              hipStream_t stream) {
    (void)in_sizes; (void)n_in; (void)out_size; (void)d_ws; (void)ws_size;
    const float* x = (const float*)d_in[0];
    const int* idxs = (const int*)d_in[1];
    // 3072 signals = 1536 pairs, one pair per block
    ista_fft_kernel<<<dim3(1536), dim3(256), 0, stream>>>(x, idxs, (float*)d_out);
}

// Round 9
// 1484.262 us; speedup vs baseline: 1.4211x; 1.4211x over previous
//
#include <hip/hip_runtime.h>
#include <math.h>

// ============================================================================
// Persistent FFT ISTA solver, radix-8, pair-packed, WAVE-LOCAL-BARRIER edition.
//
// Math per signal (identical recurrence to r1..r8, all PASSED):
//   u_{t+1} = u_t - 0.05*(I-P)*clamp20(u_t),  u_0 = 100*DCT(scatter(x[idxs]))
//   P*h = DCT2(mask(IDCT(h))),  out = 0.01*IDCT(u_99 - 0.05*clamp20(u_99)).
// Pair packing (r7, verified): signals (2p, 2p+1) share one complex FFT;
//   V-build uses P = X0k+X1N, Q = X0N-X1k; DCT2 split via conj-symmetry.
//
// r8 -> r9: REVERT r8's register-g (VGPR 132 > 128 bucket, occupancy 12%,
// 2109us) back to r7's LDS gp (VGPR 100, 1653us). Then two changes:
//  (1) Drop the 4 WAVE-LOCAL barriers per iteration (8 -> 4). For wave w
//      (t in [64w,64w+64)), stages S1,S2,S3/mask/T0,T1,T2 touch only slots
//      [512w,512w+512) (t5 = t>>5 partitions; SWZ only permutes bits 2-4
//      within a 256-group). Intra-wave LDS dataflow needs no __syncthreads:
//      compiler preserves store->load order through may-alias wk accesses
//      and emits the lgkmcnt wait; DS ops in a wave complete in order.
//      Cross-wave (stride-256 A0j, conj-partner, gp k<->N-k) barriers stay.
//  (2) PPB 2 -> 1 (grid 1536): LDS 33 KB fits 4 resident blocks/CU (was
//      grid-pinned at 3) -> +33% waves for latency hiding.
//
// Kept (r6-verified spill fix, FETCH 23GB -> 12MB): only 15 scalar
// loop-invariants, re-anchored per iteration with empty asm; twiddle powers
// rebuilt per stage by chained cmul. DO NOT REMOVE.
//
// FFT: 2048 = 8*8*8*4, 256 threads, 8 cf/thread.
//   Slot p = 256b' + 32c' + 4d' + e' holds Y[m], m = b' + 8c' + 64d' + 512e'.
//   LDS XOR-swizzle swz(p) = p ^ (((p>>5)&7)<<2), conflict-minimal stages.
// ============================================================================

#define PIF 3.14159265358979323846f
#define C0F 0.022097086912079608f      // sqrt(1/2048)
#define TWOC0 0.044194173824159216f    // 2*sqrt(1/2048)
#define CNF 0.03125f                   // sqrt(2/2048)

typedef float2 cf;

__device__ __forceinline__ int load_idx(const int* p, int j) {
    return (p[1] == 0) ? p[2 * j] : p[j];   // int64 (lo,0) pairs or int32
}
__device__ __forceinline__ int pinv(int m) {   // frequency -> slot
    return ((m & 7) << 8) | (((m >> 3) & 7) << 5) | (((m >> 6) & 7) << 2) | ((m >> 9) & 3);
}
__device__ __forceinline__ int permf(int p) {  // slot -> frequency
    return (p >> 8) | (((p >> 5) & 7) << 3) | (((p >> 2) & 7) << 6) | ((p & 3) << 9);
}
__device__ __forceinline__ float clamp20(float g) {
    return fminf(fmaxf(20.f * g, -1.f), 1.f);
}
__device__ __forceinline__ cf cadd(cf a, cf b) { return make_float2(a.x + b.x, a.y + b.y); }
__device__ __forceinline__ cf csub(cf a, cf b) { return make_float2(a.x - b.x, a.y - b.y); }
__device__ __forceinline__ cf cmul(cf a, cf b) {
    return make_float2(a.x * b.x - a.y * b.y, a.x * b.y + a.y * b.x);
}
__device__ __forceinline__ cf cmulc(cf a, cf b) {   // a * conj(b)
    return make_float2(a.x * b.x + a.y * b.y, a.y * b.x - a.x * b.y);
}
template <int S> __device__ __forceinline__ cf imul(cf z) {  // (S*i)*z
    return (S > 0) ? make_float2(-z.y, z.x) : make_float2(z.y, -z.x);
}

template <int S>
__device__ __forceinline__ void dft8r(cf& v0, cf& v1, cf& v2, cf& v3,
                                      cf& v4, cf& v5, cf& v6, cf& v7) {
    const float R2 = 0.70710678118654752f;
    cf A0 = cadd(v0, v4), D0 = csub(v0, v4);
    cf A1 = cadd(v1, v5), D1 = csub(v1, v5);
    cf A2 = cadd(v2, v6), D2 = csub(v2, v6);
    cf A3 = cadd(v3, v7), D3 = csub(v3, v7);
    const cf w8  = make_float2(R2, (S > 0) ? R2 : -R2);
    const cf w83 = make_float2(-R2, (S > 0) ? R2 : -R2);
    D1 = cmul(D1, w8);
    D2 = imul<S>(D2);
    D3 = cmul(D3, w83);
    cf E0 = cadd(A0, A2), E1 = csub(A0, A2);
    cf O0 = cadd(A1, A3), O1 = imul<S>(csub(A1, A3));
    cf F0 = cadd(D0, D2), F1 = csub(D0, D2);
    cf P0 = cadd(D1, D3), P1 = imul<S>(csub(D1, D3));
    v0 = cadd(E0, O0); v2 = cadd(E1, O1);
    v4 = csub(E0, O0); v6 = csub(E1, O1);
    v1 = cadd(F0, P0); v3 = cadd(F1, P1);
    v5 = csub(F0, P0); v7 = csub(F1, P1);
}

template <int S>
__device__ __forceinline__ void dft4r(cf& v0, cf& v1, cf& v2, cf& v3) {
    cf E0 = cadd(v0, v2), E1 = csub(v0, v2);
    cf O0 = cadd(v1, v3), O1 = imul<S>(csub(v1, v3));
    v0 = cadd(E0, O0); v1 = cadd(E1, O1);
    v2 = csub(E0, O0); v3 = csub(E1, O1);
}

// cos/sin(pi*b/16) literals, b = 0..7
#define CRL0 1.0f
#define CRL1 0.980785280403230449f
#define CRL2 0.923879532511286756f
#define CRL3 0.831469612302545237f
#define CRL4 0.707106781186547524f
#define CRL5 0.555570233019602225f
#define CRL6 0.382683432365089772f
#define CRL7 0.195090322016128268f
#define SRL0 0.0f
#define SRL1 CRL7
#define SRL2 CRL6
#define SRL3 CRL5
#define SRL4 CRL4
#define SRL5 CRL3
#define SRL6 CRL2
#define SRL7 CRL1

#define SWZ(p) ((p) ^ ((((p) >> 5) & 7) << 2))
#define A0j(j) (tswv + 256 * (j))
#define A1j(j) ((s1bv ^ ((j) << 2)) + 32 * (j) + 256 * t5v)
#define A2j(j) (s2kv + 4 * ((j) ^ s2cv) + 32 * s2cv + 256 * t5v)

#define LOAD8(A) cf v0 = wk[A(0)], v1 = wk[A(1)], v2 = wk[A(2)], v3 = wk[A(3)], \
                    v4 = wk[A(4)], v5 = wk[A(5)], v6 = wk[A(6)], v7 = wk[A(7)]
#define STORE8(A) wk[A(0)] = v0; wk[A(1)] = v1; wk[A(2)] = v2; wk[A(3)] = v3; \
                  wk[A(4)] = v4; wk[A(5)] = v5; wk[A(6)] = v6; wk[A(7)] = v7

// chained twiddle powers from the generator (PX,PY): w walks P^1..P^7
#define TWCHAINF(PX, PY) { const cf P_ = make_float2((PX), (PY)); cf w_ = P_; \
    v1 = cmul(v1, w_); w_ = cmul(w_, P_); v2 = cmul(v2, w_); w_ = cmul(w_, P_); \
    v3 = cmul(v3, w_); w_ = cmul(w_, P_); v4 = cmul(v4, w_); w_ = cmul(w_, P_); \
    v5 = cmul(v5, w_); w_ = cmul(w_, P_); v6 = cmul(v6, w_); w_ = cmul(w_, P_); \
    v7 = cmul(v7, w_); }
#define TWCHAINB(PX, PY) { const cf P_ = make_float2((PX), (PY)); cf w_ = P_; \
    v1 = cmulc(v1, w_); w_ = cmul(w_, P_); v2 = cmulc(v2, w_); w_ = cmul(w_, P_); \
    v3 = cmulc(v3, w_); w_ = cmul(w_, P_); v4 = cmulc(v4, w_); w_ = cmul(w_, P_); \
    v5 = cmulc(v5, w_); w_ = cmul(w_, P_); v6 = cmulc(v6, w_); w_ = cmul(w_, P_); \
    v7 = cmulc(v7, w_); }

#define DIFMID(A, PX, PY) { LOAD8(A); dft8r<1>(v0, v1, v2, v3, v4, v5, v6, v7); \
                            TWCHAINF(PX, PY); STORE8(A); }
#define DITMID(A, PX, PY) { LOAD8(A); TWCHAINB(PX, PY); \
                            dft8r<-1>(v0, v1, v2, v3, v4, v5, v6, v7); STORE8(A); }

// Packed V-build: V_pair[k] = V_s[k] + i*V_{s+1}[k] reduces to the single-
// signal form with P = X0k + X1N, Q = X0N - X1k (verified incl. k=0).
#define MKVBP(b, vo) { \
    const int k_ = ta + 256 * (b); \
    const int kN_ = (2048 - k_) & 2047; \
    const cf ga_ = gp[k_], gN_ = gp[kN_]; \
    float h0k_, h0N_, h1k_, h1N_; \
    if (fin) { h0k_ = ga_.x - 0.05f * clamp20(ga_.x); h0N_ = gN_.x - 0.05f * clamp20(gN_.x); \
               h1k_ = ga_.y - 0.05f * clamp20(ga_.y); h1N_ = gN_.y - 0.05f * clamp20(gN_.y); } \
    else     { h0k_ = clamp20(ga_.x); h0N_ = clamp20(gN_.x); \
               h1k_ = clamp20(ga_.y); h1N_ = clamp20(gN_.y); } \
    const bool kz_ = ((b) == 0) && (ta == 0); \
    const float s_ = kz_ ? TWOC0 : CNF; \
    const float X0k_ = s_ * h0k_, X1k_ = s_ * h1k_; \
    const float X0N_ = kz_ ? 0.f : CNF * h0N_; \
    const float X1N_ = kz_ ? 0.f : CNF * h1N_; \
    const float Pp_ = X0k_ + X1N_, Qq_ = X0N_ - X1k_; \
    const float cc_ = c0a * (CRL##b) - s0a * (SRL##b); \
    const float ss_ = s0a * (CRL##b) + c0a * (SRL##b); \
    vo = make_float2(0.5f * (Pp_ * cc_ + Qq_ * ss_), 0.5f * (Pp_ * ss_ - Qq_ * cc_)); }

#define HEADP(finv) { \
    const bool fin = (finv); \
    cf v0, v1, v2, v3, v4, v5, v6, v7; \
    MKVBP(0, v0) MKVBP(1, v1) MKVBP(2, v2) MKVBP(3, v3) \
    MKVBP(4, v4) MKVBP(5, v5) MKVBP(6, v6) MKVBP(7, v7) \
    dft8r<1>(v0, v1, v2, v3, v4, v5, v6, v7); \
    TWCHAINF(cww, sww); STORE8(A0j); }

// Tail per-k: split packed spectrum via conj-symmetry, DCT-II epilogue,
// update both signals. partner Y[Nk] read from wk (stored pre-barrier).
#define TPJ(j) { \
    const int k_ = ta + 256 * (j); \
    const int kp_ = (2048 - k_) & 2047; \
    const cf pz_ = wk[SWZ(kp_)]; \
    const float cc_ = c0a * (CRL##j) - s0a * (SRL##j); \
    const float ss_ = s0a * (CRL##j) + c0a * (SRL##j); \
    const float C0_ = 0.5f * (cc_ * (v##j.x + pz_.x) + ss_ * (v##j.y - pz_.y)); \
    const float C1_ = 0.5f * (cc_ * (v##j.y + pz_.y) + ss_ * (pz_.x - v##j.x)); \
    const float ck_ = ((((j) == 0) && (ta == 0)) ? C0F : CNF); \
    const float u0_ = ck_ * C0_, u1_ = ck_ * C1_; \
    if (init) { gp[k_] = make_float2(u0_, u1_); } \
    else { const cf go_ = gp[k_]; \
           gp[k_] = make_float2(go_.x + 0.05f * (u0_ - clamp20(go_.x)), \
                                go_.y + 0.05f * (u1_ - clamp20(go_.y))); } }

#define TAILP(initv) { \
    const bool init = (initv); \
    LOAD8(A0j); TWCHAINB(cww, sww); dft8r<-1>(v0, v1, v2, v3, v4, v5, v6, v7); \
    STORE8(A0j); \
    __syncthreads(); \
    TPJ(0) TPJ(1) TPJ(2) TPJ(3) TPJ(4) TPJ(5) TPJ(6) TPJ(7) }

// S3 + mask + T0 in registers; mask multiplies BOTH components (packed pair)
#define QUADMASK(q) { \
    const int pb_ = 8 * ta + 4 * (q); \
    const int a_ = SWZ(pb_); \
    float4 lo_ = *(const float4*)(&wk[a_]); \
    float4 hi_ = *(const float4*)(&wk[a_ + 2]); \
    cf u0 = make_float2(lo_.x, lo_.y), u1 = make_float2(lo_.z, lo_.w); \
    cf u2 = make_float2(hi_.x, hi_.y), u3 = make_float2(hi_.z, hi_.w); \
    dft4r<1>(u0, u1, u2, u3); \
    { const float k0_ = (float)((mskv >> (4 * (q) + 0)) & 1u); u0.x *= k0_; u0.y *= k0_; } \
    { const float k1_ = (float)((mskv >> (4 * (q) + 1)) & 1u); u1.x *= k1_; u1.y *= k1_; } \
    { const float k2_ = (float)((mskv >> (4 * (q) + 2)) & 1u); u2.x *= k2_; u2.y *= k2_; } \
    { const float k3_ = (float)((mskv >> (4 * (q) + 3)) & 1u); u3.x *= k3_; u3.y *= k3_; } \
    dft4r<-1>(u0, u1, u2, u3); \
    *(float4*)(&wk[a_])     = make_float4(u0.x, u0.y, u1.x, u1.y); \
    *(float4*)(&wk[a_ + 2]) = make_float4(u2.x, u2.y, u3.x, u3.y); }

#define QUADT0(q) { \
    const int pb_ = 8 * ta + 4 * (q); \
    const int a_ = SWZ(pb_); \
    float4 lo_ = *(const float4*)(&wk[a_]); \
    float4 hi_ = *(const float4*)(&wk[a_ + 2]); \
    cf u0 = make_float2(lo_.x, lo_.y), u1 = make_float2(lo_.z, lo_.w); \
    cf u2 = make_float2(hi_.x, hi_.y), u3 = make_float2(hi_.z, hi_.w); \
    dft4r<-1>(u0, u1, u2, u3); \
    *(float4*)(&wk[a_])     = make_float4(u0.x, u0.y, u1.x, u1.y); \
    *(float4*)(&wk[a_ + 2]) = make_float4(u2.x, u2.y, u3.x, u3.y); }

// THE r6-verified spill fix: re-anchor the 15 scalar invariants so LICM can't
// hoist derived values (FETCH 23GB -> 12MB when applied). Do not remove.
#define ANCHOR() asm volatile("" \
    : "+v"(cww), "+v"(sww), "+v"(coo), "+v"(soo), "+v"(cll), "+v"(sll), \
      "+v"(c0a), "+v"(s0a), "+v"(ta), "+v"(tswv), "+v"(s1bv), "+v"(t5v), \
      "+v"(s2kv), "+v"(s2cv), "+v"(mskv))

__global__ __launch_bounds__(256) void ista_fft_kernel(
    const float* __restrict__ x, const int* __restrict__ idxs,
    float* __restrict__ out)
{
    __shared__ __align__(16) cf wk[2048];   // 16 KB, swizzled slot space
    __shared__ __align__(16) cf gp[2048];   // 16 KB: gp[k] = (u_s[k], u_{s+1}[k])
    __shared__ unsigned mbm[64];

    const int t = threadIdx.x;
    int ta   = t;
    int t5v  = t >> 5;
    int s1bv = t & 31;
    int s2kv = t & 3;
    int s2cv = (t >> 2) & 7;
    int tswv = SWZ(t);

    if (t < 64) mbm[t] = 0u;
    __syncthreads();

    const int mi0 = load_idx(idxs, t), mi1 = load_idx(idxs, t + 256);
    const int yd0 = (mi0 & 1) ? (2047 - (mi0 >> 1)) : (mi0 >> 1);
    const int yd1 = (mi1 & 1) ? (2047 - (mi1 >> 1)) : (mi1 >> 1);
    const int pm0 = pinv(yd0), pm1 = pinv(yd1);
    atomicOr(&mbm[pm0 >> 5], 1u << (pm0 & 31));
    atomicOr(&mbm[pm1 >> 5], 1u << (pm1 & 31));
    const int sl0 = SWZ(pm0), sl1 = SWZ(pm1);
    __syncthreads();
    unsigned mskv = (mbm[t >> 2] >> ((t & 3) * 8)) & 0xffu;

    // the ONLY trig state: generators + half-angle pair (8 floats)
    float s0a, c0a; sincosf(PIF * (float)t * (1.f / 4096.f), &s0a, &c0a);
    float sww, cww; sincosf(2.f * PIF * (float)t    * (1.f / 2048.f), &sww, &cww);
    float soo, coo; sincosf(2.f * PIF * (float)s1bv * (1.f / 256.f),  &soo, &coo);
    float sll, cll; sincosf(2.f * PIF * (float)s2kv * (1.f / 32.f),   &sll, &cll);

    const int r0 = 2 * blockIdx.x, r1 = r0 + 1;   // one pair per block
    ANCHOR();

    // ---- init: wk = scatter(100*(x0 + i*x1)) in swizzled slot space ----
#pragma unroll
    for (int j = 0; j < 8; ++j) wk[t + 256 * j] = make_float2(0.f, 0.f);
    __syncthreads();
    wk[sl0] = make_float2(100.f * x[(size_t)r0 * 2048 + mi0],
                          100.f * x[(size_t)r1 * 2048 + mi0]);
    wk[sl1] = make_float2(100.f * x[(size_t)r0 * 2048 + mi1],
                          100.f * x[(size_t)r1 * 2048 + mi1]);
    __syncthreads();                          // scatter is cross-wave
    QUADT0(0) QUADT0(1)                       // T0 (input pre-masked)
    // T0 -> T1 -> T2 are wave-local: no barriers
    DITMID(A2j, cll, sll);                    // T1
    DITMID(A1j, coo, soo);                    // T2
    __syncthreads();                          // T2 -> TAILP A0j is cross-wave
    TAILP(true);           __syncthreads();   // gp = (u0_s, u0_{s+1})

    // ---- 99 iterations (per pair) ----
#pragma unroll 1
    for (int it = 0; it < 99; ++it) {
        ANCHOR();
        HEADP(false);          __syncthreads();   // S0 store (A0j) cross-wave
        DIFMID(A1j, coo, soo);                    // S1   } wave-local chain:
        DIFMID(A2j, cll, sll);                    // S2   } each wave touches
        QUADMASK(0) QUADMASK(1)                   // S3+mask+T0 } only its own
        DITMID(A2j, cll, sll);                    // T1   } 512-slot range
        DITMID(A1j, coo, soo);                    // T2   }
        __syncthreads();                          // T2 -> TAILP A0j cross-wave
        TAILP(false);          __syncthreads();   // split + gp update
    }

    // ---- final: out_s = 0.01*Re, out_{s+1} = 0.01*Im of IDCT(F') ----
    ANCHOR();
    HEADP(true);           __syncthreads();
    DIFMID(A1j, coo, soo);                        // wave-local
    DIFMID(A2j, cll, sll);                        // wave-local
    {   // S3 into regs (wave-local reads), then scatter to x-order through wk
        cf e0, e1, e2, e3, e4, e5, e6, e7;
        {
            const int a_ = SWZ(8 * ta);
            float4 lo_ = *(const float4*)(&wk[a_]);
            float4 hi_ = *(const float4*)(&wk[a_ + 2]);
            e0 = make_float2(lo_.x, lo_.y); e1 = make_float2(lo_.z, lo_.w);
            e2 = make_float2(hi_.x, hi_.y); e3 = make_float2(hi_.z, hi_.w);
            dft4r<1>(e0, e1, e2, e3);
        }
        {
            const int a_ = SWZ(8 * ta + 4);
            float4 lo_ = *(const float4*)(&wk[a_]);
            float4 hi_ = *(const float4*)(&wk[a_ + 2]);
            e4 = make_float2(lo_.x, lo_.y); e5 = make_float2(lo_.z, lo_.w);
            e6 = make_float2(hi_.x, hi_.y); e7 = make_float2(hi_.z, hi_.w);
            dft4r<1>(e4, e5, e6, e7);
        }
        __syncthreads();   // all quad reads done before wk is repurposed
#define FSC(e, off) { \
        const int m_ = permf(8 * ta + (off)); \
        const int i_ = (m_ < 1024) ? (m_ << 1) : (4095 - (m_ << 1)); \
        wk[i_] = make_float2(0.01f * e.x, 0.01f * e.y); }
        FSC(e0, 0) FSC(e1, 1) FSC(e2, 2) FSC(e3, 3)
        FSC(e4, 4) FSC(e5, 5) FSC(e6, 6) FSC(e7, 7)
#undef FSC
        __syncthreads();
#pragma unroll
        for (int j = 0; j < 8; ++j) {
            const cf o_ = wk[t + 256 * j];
            out[(size_t)r0 * 2048 + t + 256 * j] = o_.x;
            out[(size_t)r1 * 2048 + t + 256 * j] = o_.y;
        }
    }
}

extern "C" void kernel_launch(void* const* d_in, const int* in_sizes, int n_in,
                              void* d_out, int out_size, void* d_ws, size_t ws_size,
                              hipStream_t stream) {
    (void)in_sizes; (void)n_in; (void)out_size; (void)d_ws; (void)ws_size;
    const float* x = (const float*)d_in[0];
    const int* idxs = (const int*)d_in[1];
    // 3072 signals = 1536 pairs, ONE pair per block (4 resident blocks/CU)
    ista_fft_kernel<<<dim3(1536), dim3(256), 0, stream>>>(x, idxs, (float*)d_out);
}

// Round 10
// 1269.929 us; speedup vs baseline: 1.6610x; 1.1688x over previous
//
#include <hip/hip_runtime.h>
#include <math.h>

// ============================================================================
// Persistent FFT ISTA solver, radix-8, pair-packed, PACKED-FP32 edition.
//
// Math per signal (identical recurrence to r1..r9, all PASSED):
//   u_{t+1} = u_t - 0.05*(I-P)*clamp20(u_t),  u_0 = 100*DCT(scatter(x[idxs]))
//   P*h = DCT2(mask(IDCT(h))),  out = 0.01*IDCT(u_99 - 0.05*clamp20(u_99)).
// Pair packing (r7): signals (2p,2p+1) share one complex FFT; V-build uses
//   P = X0k+X1N, Q = X0N-X1k; DCT2 split via conj-symmetry.
//
// r9 -> r10 (ONE isolated change): complex type float2 (struct, scalar ops)
// -> ext_vector_type(2) float (true <2 x float>). gfx950 has full-rate
// v_pk_{add,mul,fma}_f32 (VOP3P; op_sel swizzle + per-lane neg are free
// modifiers). Complex ops in swizzle form:
//   cadd = a+b                      : 1 pk_add   (was 2 instr)
//   cmul = a.xx*b + (-a.y,a.y)*b.yx : pk_mul+pk_fma (was 4)
//   cmulc= a.xx*(b.x,-b.y) + a.yy*b.yx : 2       (was 4)
// -> ~halves VALU instruction count; kernel was VALU-issue bound (73% busy,
// instr model 3.3e6 of 4.0e6 cyc/CU). Structure/barriers/LDS byte-identical
// to r9 (wave-local barrier elision verified there).
//
// Kept (r6-verified spill fix, FETCH 23GB -> 12MB): 15 scalar loop-invariants
// re-anchored per iteration with empty asm; twiddle powers rebuilt per stage
// by chained cmul. DO NOT REMOVE.
//
// FFT: 2048 = 8*8*8*4, 256 threads, 8 cf/thread.
//   Slot p = 256b' + 32c' + 4d' + e' holds Y[m], m = b' + 8c' + 64d' + 512e'.
//   LDS XOR-swizzle swz(p) = p ^ (((p>>5)&7)<<2), conflict-minimal stages.
//   Wave-local stages S1,S2,S3/mask/T0,T1,T2 run barrier-free (r9-verified).
// ============================================================================

#define PIF 3.14159265358979323846f
#define C0F 0.022097086912079608f      // sqrt(1/2048)
#define TWOC0 0.044194173824159216f    // 2*sqrt(1/2048)
#define CNF 0.03125f                   // sqrt(2/2048)

typedef float cf __attribute__((ext_vector_type(2)));   // complex as <2 x float>

__device__ __forceinline__ cf mk(float x, float y) { cf r; r.x = x; r.y = y; return r; }

__device__ __forceinline__ int load_idx(const int* p, int j) {
    return (p[1] == 0) ? p[2 * j] : p[j];   // int64 (lo,0) pairs or int32
}
__device__ __forceinline__ int pinv(int m) {   // frequency -> slot
    return ((m & 7) << 8) | (((m >> 3) & 7) << 5) | (((m >> 6) & 7) << 2) | ((m >> 9) & 3);
}
__device__ __forceinline__ int permf(int p) {  // slot -> frequency
    return (p >> 8) | (((p >> 5) & 7) << 3) | (((p >> 2) & 7) << 6) | ((p & 3) << 9);
}
__device__ __forceinline__ float clamp20(float g) {
    return fminf(fmaxf(20.f * g, -1.f), 1.f);
}
__device__ __forceinline__ cf cadd(cf a, cf b) { return a + b; }
__device__ __forceinline__ cf csub(cf a, cf b) { return a - b; }
__device__ __forceinline__ cf cmul(cf a, cf b) {
    // (re,im) = a.xx*b + (-a.y, a.y)*b.yx   -> v_pk_mul + v_pk_fma
    return a.xx * b + mk(-a.y, a.y) * b.yx;
}
__device__ __forceinline__ cf cmulc(cf a, cf b) {   // a * conj(b)
    // lane0: a.x*b.x + a.y*b.y ; lane1: -a.x*b.y + a.y*b.x
    return a.xx * mk(b.x, -b.y) + a.yy * b.yx;
}
template <int S> __device__ __forceinline__ cf imul(cf z) {  // (S*i)*z
    return (S > 0) ? mk(-z.y, z.x) : mk(z.y, -z.x);
}

template <int S>
__device__ __forceinline__ void dft8r(cf& v0, cf& v1, cf& v2, cf& v3,
                                      cf& v4, cf& v5, cf& v6, cf& v7) {
    const float R2 = 0.70710678118654752f;
    cf A0 = cadd(v0, v4), D0 = csub(v0, v4);
    cf A1 = cadd(v1, v5), D1 = csub(v1, v5);
    cf A2 = cadd(v2, v6), D2 = csub(v2, v6);
    cf A3 = cadd(v3, v7), D3 = csub(v3, v7);
    const cf w8  = mk(R2, (S > 0) ? R2 : -R2);
    const cf w83 = mk(-R2, (S > 0) ? R2 : -R2);
    D1 = cmul(D1, w8);
    D2 = imul<S>(D2);
    D3 = cmul(D3, w83);
    cf E0 = cadd(A0, A2), E1 = csub(A0, A2);
    cf O0 = cadd(A1, A3), O1 = imul<S>(csub(A1, A3));
    cf F0 = cadd(D0, D2), F1 = csub(D0, D2);
    cf P0 = cadd(D1, D3), P1 = imul<S>(csub(D1, D3));
    v0 = cadd(E0, O0); v2 = cadd(E1, O1);
    v4 = csub(E0, O0); v6 = csub(E1, O1);
    v1 = cadd(F0, P0); v3 = cadd(F1, P1);
    v5 = csub(F0, P0); v7 = csub(F1, P1);
}

template <int S>
__device__ __forceinline__ void dft4r(cf& v0, cf& v1, cf& v2, cf& v3) {
    cf E0 = cadd(v0, v2), E1 = csub(v0, v2);
    cf O0 = cadd(v1, v3), O1 = imul<S>(csub(v1, v3));
    v0 = cadd(E0, O0); v1 = cadd(E1, O1);
    v2 = csub(E0, O0); v3 = csub(E1, O1);
}

// cos/sin(pi*b/16) literals, b = 0..7
#define CRL0 1.0f
#define CRL1 0.980785280403230449f
#define CRL2 0.923879532511286756f
#define CRL3 0.831469612302545237f
#define CRL4 0.707106781186547524f
#define CRL5 0.555570233019602225f
#define CRL6 0.382683432365089772f
#define CRL7 0.195090322016128268f
#define SRL0 0.0f
#define SRL1 CRL7
#define SRL2 CRL6
#define SRL3 CRL5
#define SRL4 CRL4
#define SRL5 CRL3
#define SRL6 CRL2
#define SRL7 CRL1

#define SWZ(p) ((p) ^ ((((p) >> 5) & 7) << 2))
#define A0j(j) (tswv + 256 * (j))
#define A1j(j) ((s1bv ^ ((j) << 2)) + 32 * (j) + 256 * t5v)
#define A2j(j) (s2kv + 4 * ((j) ^ s2cv) + 32 * s2cv + 256 * t5v)

#define LOAD8(A) cf v0 = wk[A(0)], v1 = wk[A(1)], v2 = wk[A(2)], v3 = wk[A(3)], \
                    v4 = wk[A(4)], v5 = wk[A(5)], v6 = wk[A(6)], v7 = wk[A(7)]
#define STORE8(A) wk[A(0)] = v0; wk[A(1)] = v1; wk[A(2)] = v2; wk[A(3)] = v3; \
                  wk[A(4)] = v4; wk[A(5)] = v5; wk[A(6)] = v6; wk[A(7)] = v7

// chained twiddle powers from the generator (PX,PY): w walks P^1..P^7
#define TWCHAINF(PX, PY) { const cf P_ = mk((PX), (PY)); cf w_ = P_; \
    v1 = cmul(v1, w_); w_ = cmul(w_, P_); v2 = cmul(v2, w_); w_ = cmul(w_, P_); \
    v3 = cmul(v3, w_); w_ = cmul(w_, P_); v4 = cmul(v4, w_); w_ = cmul(w_, P_); \
    v5 = cmul(v5, w_); w_ = cmul(w_, P_); v6 = cmul(v6, w_); w_ = cmul(w_, P_); \
    v7 = cmul(v7, w_); }
#define TWCHAINB(PX, PY) { const cf P_ = mk((PX), (PY)); cf w_ = P_; \
    v1 = cmulc(v1, w_); w_ = cmul(w_, P_); v2 = cmulc(v2, w_); w_ = cmul(w_, P_); \
    v3 = cmulc(v3, w_); w_ = cmul(w_, P_); v4 = cmulc(v4, w_); w_ = cmul(w_, P_); \
    v5 = cmulc(v5, w_); w_ = cmul(w_, P_); v6 = cmulc(v6, w_); w_ = cmul(w_, P_); \
    v7 = cmulc(v7, w_); }

#define DIFMID(A, PX, PY) { LOAD8(A); dft8r<1>(v0, v1, v2, v3, v4, v5, v6, v7); \
                            TWCHAINF(PX, PY); STORE8(A); }
#define DITMID(A, PX, PY) { LOAD8(A); TWCHAINB(PX, PY); \
                            dft8r<-1>(v0, v1, v2, v3, v4, v5, v6, v7); STORE8(A); }

// Packed V-build: V_pair[k] = V_s[k] + i*V_{s+1}[k] reduces to the single-
// signal form with P = X0k + X1N, Q = X0N - X1k (verified incl. k=0).
#define MKVBP(b, vo) { \
    const int k_ = ta + 256 * (b); \
    const int kN_ = (2048 - k_) & 2047; \
    const cf ga_ = gp[k_], gN_ = gp[kN_]; \
    float h0k_, h0N_, h1k_, h1N_; \
    if (fin) { h0k_ = ga_.x - 0.05f * clamp20(ga_.x); h0N_ = gN_.x - 0.05f * clamp20(gN_.x); \
               h1k_ = ga_.y - 0.05f * clamp20(ga_.y); h1N_ = gN_.y - 0.05f * clamp20(gN_.y); } \
    else     { h0k_ = clamp20(ga_.x); h0N_ = clamp20(gN_.x); \
               h1k_ = clamp20(ga_.y); h1N_ = clamp20(gN_.y); } \
    const bool kz_ = ((b) == 0) && (ta == 0); \
    const float s_ = kz_ ? TWOC0 : CNF; \
    const float X0k_ = s_ * h0k_, X1k_ = s_ * h1k_; \
    const float X0N_ = kz_ ? 0.f : CNF * h0N_; \
    const float X1N_ = kz_ ? 0.f : CNF * h1N_; \
    const float Pp_ = X0k_ + X1N_, Qq_ = X0N_ - X1k_; \
    const float cc_ = c0a * (CRL##b) - s0a * (SRL##b); \
    const float ss_ = s0a * (CRL##b) + c0a * (SRL##b); \
    vo = mk(0.5f * (Pp_ * cc_ + Qq_ * ss_), 0.5f * (Pp_ * ss_ - Qq_ * cc_)); }

#define HEADP(finv) { \
    const bool fin = (finv); \
    cf v0, v1, v2, v3, v4, v5, v6, v7; \
    MKVBP(0, v0) MKVBP(1, v1) MKVBP(2, v2) MKVBP(3, v3) \
    MKVBP(4, v4) MKVBP(5, v5) MKVBP(6, v6) MKVBP(7, v7) \
    dft8r<1>(v0, v1, v2, v3, v4, v5, v6, v7); \
    TWCHAINF(cww, sww); STORE8(A0j); }

// Tail per-k: split packed spectrum via conj-symmetry, DCT-II epilogue,
// update both signals. partner Y[Nk] read from wk (stored pre-barrier).
#define TPJ(j) { \
    const int k_ = ta + 256 * (j); \
    const int kp_ = (2048 - k_) & 2047; \
    const cf pz_ = wk[SWZ(kp_)]; \
    const float cc_ = c0a * (CRL##j) - s0a * (SRL##j); \
    const float ss_ = s0a * (CRL##j) + c0a * (SRL##j); \
    const float C0_ = 0.5f * (cc_ * (v##j.x + pz_.x) + ss_ * (v##j.y - pz_.y)); \
    const float C1_ = 0.5f * (cc_ * (v##j.y + pz_.y) + ss_ * (pz_.x - v##j.x)); \
    const float ck_ = ((((j) == 0) && (ta == 0)) ? C0F : CNF); \
    const float u0_ = ck_ * C0_, u1_ = ck_ * C1_; \
    if (init) { gp[k_] = mk(u0_, u1_); } \
    else { const cf go_ = gp[k_]; \
           gp[k_] = mk(go_.x + 0.05f * (u0_ - clamp20(go_.x)), \
                       go_.y + 0.05f * (u1_ - clamp20(go_.y))); } }

#define TAILP(initv) { \
    const bool init = (initv); \
    LOAD8(A0j); TWCHAINB(cww, sww); dft8r<-1>(v0, v1, v2, v3, v4, v5, v6, v7); \
    STORE8(A0j); \
    __syncthreads(); \
    TPJ(0) TPJ(1) TPJ(2) TPJ(3) TPJ(4) TPJ(5) TPJ(6) TPJ(7) }

// S3 + mask + T0 in registers; mask multiplies BOTH components (packed pair)
#define QUADMASK(q) { \
    const int pb_ = 8 * ta + 4 * (q); \
    const int a_ = SWZ(pb_); \
    float4 lo_ = *(const float4*)(&wk[a_]); \
    float4 hi_ = *(const float4*)(&wk[a_ + 2]); \
    cf u0 = mk(lo_.x, lo_.y), u1 = mk(lo_.z, lo_.w); \
    cf u2 = mk(hi_.x, hi_.y), u3 = mk(hi_.z, hi_.w); \
    dft4r<1>(u0, u1, u2, u3); \
    u0 = u0 * (float)((mskv >> (4 * (q) + 0)) & 1u); \
    u1 = u1 * (float)((mskv >> (4 * (q) + 1)) & 1u); \
    u2 = u2 * (float)((mskv >> (4 * (q) + 2)) & 1u); \
    u3 = u3 * (float)((mskv >> (4 * (q) + 3)) & 1u); \
    dft4r<-1>(u0, u1, u2, u3); \
    *(float4*)(&wk[a_])     = make_float4(u0.x, u0.y, u1.x, u1.y); \
    *(float4*)(&wk[a_ + 2]) = make_float4(u2.x, u2.y, u3.x, u3.y); }

#define QUADT0(q) { \
    const int pb_ = 8 * ta + 4 * (q); \
    const int a_ = SWZ(pb_); \
    float4 lo_ = *(const float4*)(&wk[a_]); \
    float4 hi_ = *(const float4*)(&wk[a_ + 2]); \
    cf u0 = mk(lo_.x, lo_.y), u1 = mk(lo_.z, lo_.w); \
    cf u2 = mk(hi_.x, hi_.y), u3 = mk(hi_.z, hi_.w); \
    dft4r<-1>(u0, u1, u2, u3); \
    *(float4*)(&wk[a_])     = make_float4(u0.x, u0.y, u1.x, u1.y); \
    *(float4*)(&wk[a_ + 2]) = make_float4(u2.x, u2.y, u3.x, u3.y); }

// THE r6-verified spill fix: re-anchor the 15 scalar invariants so LICM can't
// hoist derived values (FETCH 23GB -> 12MB when applied). Do not remove.
#define ANCHOR() asm volatile("" \
    : "+v"(cww), "+v"(sww), "+v"(coo), "+v"(soo), "+v"(cll), "+v"(sll), \
      "+v"(c0a), "+v"(s0a), "+v"(ta), "+v"(tswv), "+v"(s1bv), "+v"(t5v), \
      "+v"(s2kv), "+v"(s2cv), "+v"(mskv))

__global__ __launch_bounds__(256) void ista_fft_kernel(
    const float* __restrict__ x, const int* __restrict__ idxs,
    float* __restrict__ out)
{
    __shared__ __align__(16) cf wk[2048];   // 16 KB, swizzled slot space
    __shared__ __align__(16) cf gp[2048];   // 16 KB: gp[k] = (u_s[k], u_{s+1}[k])
    __shared__ unsigned mbm[64];

    const int t = threadIdx.x;
    int ta   = t;
    int t5v  = t >> 5;
    int s1bv = t & 31;
    int s2kv = t & 3;
    int s2cv = (t >> 2) & 7;
    int tswv = SWZ(t);

    if (t < 64) mbm[t] = 0u;
    __syncthreads();

    const int mi0 = load_idx(idxs, t), mi1 = load_idx(idxs, t + 256);
    const int yd0 = (mi0 & 1) ? (2047 - (mi0 >> 1)) : (mi0 >> 1);
    const int yd1 = (mi1 & 1) ? (2047 - (mi1 >> 1)) : (mi1 >> 1);
    const int pm0 = pinv(yd0), pm1 = pinv(yd1);
    atomicOr(&mbm[pm0 >> 5], 1u << (pm0 & 31));
    atomicOr(&mbm[pm1 >> 5], 1u << (pm1 & 31));
    const int sl0 = SWZ(pm0), sl1 = SWZ(pm1);
    __syncthreads();
    unsigned mskv = (mbm[t >> 2] >> ((t & 3) * 8)) & 0xffu;

    // the ONLY trig state: generators + half-angle pair (8 floats)
    float s0a, c0a; sincosf(PIF * (float)t * (1.f / 4096.f), &s0a, &c0a);
    float sww, cww; sincosf(2.f * PIF * (float)t    * (1.f / 2048.f), &sww, &cww);
    float soo, coo; sincosf(2.f * PIF * (float)s1bv * (1.f / 256.f),  &soo, &coo);
    float sll, cll; sincosf(2.f * PIF * (float)s2kv * (1.f / 32.f),   &sll, &cll);

    const int r0 = 2 * blockIdx.x, r1 = r0 + 1;   // one pair per block
    ANCHOR();

    // ---- init: wk = scatter(100*(x0 + i*x1)) in swizzled slot space ----
#pragma unroll
    for (int j = 0; j < 8; ++j) wk[t + 256 * j] = mk(0.f, 0.f);
    __syncthreads();
    wk[sl0] = mk(100.f * x[(size_t)r0 * 2048 + mi0],
                 100.f * x[(size_t)r1 * 2048 + mi0]);
    wk[sl1] = mk(100.f * x[(size_t)r0 * 2048 + mi1],
                 100.f * x[(size_t)r1 * 2048 + mi1]);
    __syncthreads();                          // scatter is cross-wave
    QUADT0(0) QUADT0(1)                       // T0 (input pre-masked)
    // T0 -> T1 -> T2 are wave-local: no barriers (r9-verified)
    DITMID(A2j, cll, sll);                    // T1
    DITMID(A1j, coo, soo);                    // T2
    __syncthreads();                          // T2 -> TAILP A0j is cross-wave
    TAILP(true);           __syncthreads();   // gp = (u0_s, u0_{s+1})

    // ---- 99 iterations (per pair) ----
#pragma unroll 1
    for (int it = 0; it < 99; ++it) {
        ANCHOR();
        HEADP(false);          __syncthreads();   // S0 store (A0j) cross-wave
        DIFMID(A1j, coo, soo);                    // S1   } wave-local chain:
        DIFMID(A2j, cll, sll);                    // S2   } each wave touches
        QUADMASK(0) QUADMASK(1)                   // S3+mask+T0 } only its own
        DITMID(A2j, cll, sll);                    // T1   } 512-slot range
        DITMID(A1j, coo, soo);                    // T2   }
        __syncthreads();                          // T2 -> TAILP A0j cross-wave
        TAILP(false);          __syncthreads();   // split + gp update
    }

    // ---- final: out_s = 0.01*Re, out_{s+1} = 0.01*Im of IDCT(F') ----
    ANCHOR();
    HEADP(true);           __syncthreads();
    DIFMID(A1j, coo, soo);                        // wave-local
    DIFMID(A2j, cll, sll);                        // wave-local
    {   // S3 into regs (wave-local reads), then scatter to x-order through wk
        cf e0, e1, e2, e3, e4, e5, e6, e7;
        {
            const int a_ = SWZ(8 * ta);
            float4 lo_ = *(const float4*)(&wk[a_]);
            float4 hi_ = *(const float4*)(&wk[a_ + 2]);
            e0 = mk(lo_.x, lo_.y); e1 = mk(lo_.z, lo_.w);
            e2 = mk(hi_.x, hi_.y); e3 = mk(hi_.z, hi_.w);
            dft4r<1>(e0, e1, e2, e3);
        }
        {
            const int a_ = SWZ(8 * ta + 4);
            float4 lo_ = *(const float4*)(&wk[a_]);
            float4 hi_ = *(const float4*)(&wk[a_ + 2]);
            e4 = mk(lo_.x, lo_.y); e5 = mk(lo_.z, lo_.w);
            e6 = mk(hi_.x, hi_.y); e7 = mk(hi_.z, hi_.w);
            dft4r<1>(e4, e5, e6, e7);
        }
        __syncthreads();   // all quad reads done before wk is repurposed
#define FSC(e, off) { \
        const int m_ = permf(8 * ta + (off)); \
        const int i_ = (m_ < 1024) ? (m_ << 1) : (4095 - (m_ << 1)); \
        wk[i_] = mk(0.01f * e.x, 0.01f * e.y); }
        FSC(e0, 0) FSC(e1, 1) FSC(e2, 2) FSC(e3, 3)
        FSC(e4, 4) FSC(e5, 5) FSC(e6, 6) FSC(e7, 7)
#undef FSC
        __syncthreads();
#pragma unroll
        for (int j = 0; j < 8; ++j) {
            const cf o_ = wk[t + 256 * j];
            out[(size_t)r0 * 2048 + t + 256 * j] = o_.x;
            out[(size_t)r1 * 2048 + t + 256 * j] = o_.y;
        }
    }
}

extern "C" void kernel_launch(void* const* d_in, const int* in_sizes, int n_in,
                              void* d_out, int out_size, void* d_ws, size_t ws_size,
                              hipStream_t stream) {
    (void)in_sizes; (void)n_in; (void)out_size; (void)d_ws; (void)ws_size;
    const float* x = (const float*)d_in[0];
    const int* idxs = (const int*)d_in[1];
    // 3072 signals = 1536 pairs, ONE pair per block (4 resident blocks/CU)
    ista_fft_kernel<<<dim3(1536), dim3(256), 0, stream>>>(x, idxs, (float*)d_out);
}

// Round 11
// 1210.732 us; speedup vs baseline: 1.7422x; 1.0489x over previous
//
#include <hip/hip_runtime.h>
#include <math.h>

// ============================================================================
// Persistent FFT ISTA solver, radix-8, pair-packed, packed-FP32, 32KB edition.
//
// Math per signal (identical recurrence to r1..r10, all PASSED):
//   u_{t+1} = u_t - 0.05*(I-P)*clamp20(u_t),  u_0 = 100*DCT(scatter(x[idxs]))
//   P*h = DCT2(mask(IDCT(h))),  out = 0.01*IDCT(u_99 - 0.05*clamp20(u_99)).
// Pair packing (r7): signals (2p,2p+1) share one complex FFT; V-build uses
//   P = X0k+X1N, Q = X0N-X1k; DCT2 split via conj-symmetry.
//
// r10 -> r11 (two changes):
//  (1) mbm aliased into wk storage (mask bits only live during init, before
//      wk's first use; mskv extracted to a register + one barrier). LDS drops
//      33 KB -> exactly 32768 B -> 5 resident blocks/CU (was 4): +25% waves.
//  (2) MKVBP/TPJ vectorized in the r10 swizzle algebra (verified):
//      (P,Q) = mk(Xk.x,-Xk.y) + XN.yx;  v = 0.5*cmul(mk(P,-Q), w)
//      (C0,C1) = w.x*A + w.y*mk(B.y,-B.x), A = v+pz, B = v-pz.
//
// Kept: r9 wave-local barrier elision (4 barriers/iter), r10 ext_vector cf
// (v_pk_{add,mul,fma}_f32), r6 ANCHOR spill fix (FETCH 23GB -> 12MB) —
// DO NOT REMOVE. FFT: 2048 = 8*8*8*4, 256 threads, 8 cf/thread,
// slot p = 256b'+32c'+4d'+e', swz(p) = p ^ (((p>>5)&7)<<2).
// ============================================================================

#define PIF 3.14159265358979323846f
#define C0F 0.022097086912079608f      // sqrt(1/2048)
#define TWOC0 0.044194173824159216f    // 2*sqrt(1/2048)
#define CNF 0.03125f                   // sqrt(2/2048)

typedef float cf __attribute__((ext_vector_type(2)));   // complex as <2 x float>

__device__ __forceinline__ cf mk(float x, float y) { cf r; r.x = x; r.y = y; return r; }

__device__ __forceinline__ int load_idx(const int* p, int j) {
    return (p[1] == 0) ? p[2 * j] : p[j];   // int64 (lo,0) pairs or int32
}
__device__ __forceinline__ int pinv(int m) {   // frequency -> slot
    return ((m & 7) << 8) | (((m >> 3) & 7) << 5) | (((m >> 6) & 7) << 2) | ((m >> 9) & 3);
}
__device__ __forceinline__ int permf(int p) {  // slot -> frequency
    return (p >> 8) | (((p >> 5) & 7) << 3) | (((p >> 2) & 7) << 6) | ((p & 3) << 9);
}
__device__ __forceinline__ cf clampv(cf g) {   // clamp(20*g, -1, 1) per lane
    return mk(fminf(fmaxf(20.f * g.x, -1.f), 1.f),
              fminf(fmaxf(20.f * g.y, -1.f), 1.f));
}
__device__ __forceinline__ cf cadd(cf a, cf b) { return a + b; }
__device__ __forceinline__ cf csub(cf a, cf b) { return a - b; }
__device__ __forceinline__ cf cmul(cf a, cf b) {
    return a.xx * b + mk(-a.y, a.y) * b.yx;        // pk_mul + pk_fma
}
__device__ __forceinline__ cf cmulc(cf a, cf b) {  // a * conj(b)
    return a.xx * mk(b.x, -b.y) + a.yy * b.yx;
}
template <int S> __device__ __forceinline__ cf imul(cf z) {  // (S*i)*z
    return (S > 0) ? mk(-z.y, z.x) : mk(z.y, -z.x);
}

template <int S>
__device__ __forceinline__ void dft8r(cf& v0, cf& v1, cf& v2, cf& v3,
                                      cf& v4, cf& v5, cf& v6, cf& v7) {
    const float R2 = 0.70710678118654752f;
    cf A0 = cadd(v0, v4), D0 = csub(v0, v4);
    cf A1 = cadd(v1, v5), D1 = csub(v1, v5);
    cf A2 = cadd(v2, v6), D2 = csub(v2, v6);
    cf A3 = cadd(v3, v7), D3 = csub(v3, v7);
    const cf w8  = mk(R2, (S > 0) ? R2 : -R2);
    const cf w83 = mk(-R2, (S > 0) ? R2 : -R2);
    D1 = cmul(D1, w8);
    D2 = imul<S>(D2);
    D3 = cmul(D3, w83);
    cf E0 = cadd(A0, A2), E1 = csub(A0, A2);
    cf O0 = cadd(A1, A3), O1 = imul<S>(csub(A1, A3));
    cf F0 = cadd(D0, D2), F1 = csub(D0, D2);
    cf P0 = cadd(D1, D3), P1 = imul<S>(csub(D1, D3));
    v0 = cadd(E0, O0); v2 = cadd(E1, O1);
    v4 = csub(E0, O0); v6 = csub(E1, O1);
    v1 = cadd(F0, P0); v3 = cadd(F1, P1);
    v5 = csub(F0, P0); v7 = csub(F1, P1);
}

template <int S>
__device__ __forceinline__ void dft4r(cf& v0, cf& v1, cf& v2, cf& v3) {
    cf E0 = cadd(v0, v2), E1 = csub(v0, v2);
    cf O0 = cadd(v1, v3), O1 = imul<S>(csub(v1, v3));
    v0 = cadd(E0, O0); v1 = cadd(E1, O1);
    v2 = csub(E0, O0); v3 = csub(E1, O1);
}

// cos/sin(pi*b/16) literals, b = 0..7
#define CRL0 1.0f
#define CRL1 0.980785280403230449f
#define CRL2 0.923879532511286756f
#define CRL3 0.831469612302545237f
#define CRL4 0.707106781186547524f
#define CRL5 0.555570233019602225f
#define CRL6 0.382683432365089772f
#define CRL7 0.195090322016128268f
#define SRL0 0.0f
#define SRL1 CRL7
#define SRL2 CRL6
#define SRL3 CRL5
#define SRL4 CRL4
#define SRL5 CRL3
#define SRL6 CRL2
#define SRL7 CRL1

#define SWZ(p) ((p) ^ ((((p) >> 5) & 7) << 2))
#define A0j(j) (tswv + 256 * (j))
#define A1j(j) ((s1bv ^ ((j) << 2)) + 32 * (j) + 256 * t5v)
#define A2j(j) (s2kv + 4 * ((j) ^ s2cv) + 32 * s2cv + 256 * t5v)

#define LOAD8(A) cf v0 = wk[A(0)], v1 = wk[A(1)], v2 = wk[A(2)], v3 = wk[A(3)], \
                    v4 = wk[A(4)], v5 = wk[A(5)], v6 = wk[A(6)], v7 = wk[A(7)]
#define STORE8(A) wk[A(0)] = v0; wk[A(1)] = v1; wk[A(2)] = v2; wk[A(3)] = v3; \
                  wk[A(4)] = v4; wk[A(5)] = v5; wk[A(6)] = v6; wk[A(7)] = v7

// chained twiddle powers from the generator (PX,PY): w walks P^1..P^7
#define TWCHAINF(PX, PY) { const cf P_ = mk((PX), (PY)); cf w_ = P_; \
    v1 = cmul(v1, w_); w_ = cmul(w_, P_); v2 = cmul(v2, w_); w_ = cmul(w_, P_); \
    v3 = cmul(v3, w_); w_ = cmul(w_, P_); v4 = cmul(v4, w_); w_ = cmul(w_, P_); \
    v5 = cmul(v5, w_); w_ = cmul(w_, P_); v6 = cmul(v6, w_); w_ = cmul(w_, P_); \
    v7 = cmul(v7, w_); }
#define TWCHAINB(PX, PY) { const cf P_ = mk((PX), (PY)); cf w_ = P_; \
    v1 = cmulc(v1, w_); w_ = cmul(w_, P_); v2 = cmulc(v2, w_); w_ = cmul(w_, P_); \
    v3 = cmulc(v3, w_); w_ = cmul(w_, P_); v4 = cmulc(v4, w_); w_ = cmul(w_, P_); \
    v5 = cmulc(v5, w_); w_ = cmul(w_, P_); v6 = cmulc(v6, w_); w_ = cmul(w_, P_); \
    v7 = cmulc(v7, w_); }

#define DIFMID(A, PX, PY) { LOAD8(A); dft8r<1>(v0, v1, v2, v3, v4, v5, v6, v7); \
                            TWCHAINF(PX, PY); STORE8(A); }
#define DITMID(A, PX, PY) { LOAD8(A); TWCHAINB(PX, PY); \
                            dft8r<-1>(v0, v1, v2, v3, v4, v5, v6, v7); STORE8(A); }

// Packed V-build (vectorized; algebra verified vs r7 scalar form):
//   Xk = s*clampv(g[k]); XN = (k==0?0:CNF)*clampv(g[N-k])
//   (P,Q) = mk(Xk.x,-Xk.y) + XN.yx;  w = (cc,ss) = cmul((c0a,s0a),(CRb,SRb))
//   v = 0.5 * cmul(mk(P,-Q), w)
#define MKVBP(b, vo) { \
    const int k_ = ta + 256 * (b); \
    const int kN_ = (2048 - k_) & 2047; \
    const cf ga_ = gp[k_], gN_ = gp[kN_]; \
    cf hk_, hN_; \
    if (fin) { hk_ = ga_ - 0.05f * clampv(ga_); hN_ = gN_ - 0.05f * clampv(gN_); } \
    else     { hk_ = clampv(ga_); hN_ = clampv(gN_); } \
    const bool kz_ = ((b) == 0) && (ta == 0); \
    const cf Xk_ = (kz_ ? TWOC0 : CNF) * hk_; \
    const cf XN_ = (kz_ ? 0.f : CNF) * hN_; \
    const cf PQ_ = mk(Xk_.x, -Xk_.y) + XN_.yx; \
    const cf w_ = cmul(mk(c0a, s0a), mk(CRL##b, SRL##b)); \
    vo = 0.5f * cmul(mk(PQ_.x, -PQ_.y), w_); }

#define HEADP(finv) { \
    const bool fin = (finv); \
    cf v0, v1, v2, v3, v4, v5, v6, v7; \
    MKVBP(0, v0) MKVBP(1, v1) MKVBP(2, v2) MKVBP(3, v3) \
    MKVBP(4, v4) MKVBP(5, v5) MKVBP(6, v6) MKVBP(7, v7) \
    dft8r<1>(v0, v1, v2, v3, v4, v5, v6, v7); \
    TWCHAINF(cww, sww); STORE8(A0j); }

// Tail per-k (vectorized): A = Y[k]+Y[Nk], B = Y[k]-Y[Nk];
//   (C0,C1) = w.x*A + w.y*mk(B.y,-B.x);  u = 0.5*ck*(C0,C1);  update gp.
#define TPJ(j) { \
    const int k_ = ta + 256 * (j); \
    const int kp_ = (2048 - k_) & 2047; \
    const cf pz_ = wk[SWZ(kp_)]; \
    const cf w_ = cmul(mk(c0a, s0a), mk(CRL##j, SRL##j)); \
    const cf A_ = v##j + pz_; \
    const cf B_ = v##j - pz_; \
    const cf C_ = w_.x * A_ + w_.y * mk(B_.y, -B_.x); \
    const float ckh_ = ((((j) == 0) && (ta == 0)) ? (0.5f * C0F) : (0.5f * CNF)); \
    const cf u_ = ckh_ * C_; \
    if (init) { gp[k_] = u_; } \
    else { const cf go_ = gp[k_]; \
           gp[k_] = go_ + 0.05f * (u_ - clampv(go_)); } }

#define TAILP(initv) { \
    const bool init = (initv); \
    LOAD8(A0j); TWCHAINB(cww, sww); dft8r<-1>(v0, v1, v2, v3, v4, v5, v6, v7); \
    STORE8(A0j); \
    __syncthreads(); \
    TPJ(0) TPJ(1) TPJ(2) TPJ(3) TPJ(4) TPJ(5) TPJ(6) TPJ(7) }

// S3 + mask + T0 in registers; mask multiplies BOTH components (packed pair)
#define QUADMASK(q) { \
    const int pb_ = 8 * ta + 4 * (q); \
    const int a_ = SWZ(pb_); \
    float4 lo_ = *(const float4*)(&wk[a_]); \
    float4 hi_ = *(const float4*)(&wk[a_ + 2]); \
    cf u0 = mk(lo_.x, lo_.y), u1 = mk(lo_.z, lo_.w); \
    cf u2 = mk(hi_.x, hi_.y), u3 = mk(hi_.z, hi_.w); \
    dft4r<1>(u0, u1, u2, u3); \
    u0 = u0 * (float)((mskv >> (4 * (q) + 0)) & 1u); \
    u1 = u1 * (float)((mskv >> (4 * (q) + 1)) & 1u); \
    u2 = u2 * (float)((mskv >> (4 * (q) + 2)) & 1u); \
    u3 = u3 * (float)((mskv >> (4 * (q) + 3)) & 1u); \
    dft4r<-1>(u0, u1, u2, u3); \
    *(float4*)(&wk[a_])     = make_float4(u0.x, u0.y, u1.x, u1.y); \
    *(float4*)(&wk[a_ + 2]) = make_float4(u2.x, u2.y, u3.x, u3.y); }

#define QUADT0(q) { \
    const int pb_ = 8 * ta + 4 * (q); \
    const int a_ = SWZ(pb_); \
    float4 lo_ = *(const float4*)(&wk[a_]); \
    float4 hi_ = *(const float4*)(&wk[a_ + 2]); \
    cf u0 = mk(lo_.x, lo_.y), u1 = mk(lo_.z, lo_.w); \
    cf u2 = mk(hi_.x, hi_.y), u3 = mk(hi_.z, hi_.w); \
    dft4r<-1>(u0, u1, u2, u3); \
    *(float4*)(&wk[a_])     = make_float4(u0.x, u0.y, u1.x, u1.y); \
    *(float4*)(&wk[a_ + 2]) = make_float4(u2.x, u2.y, u3.x, u3.y); }

// THE r6-verified spill fix: re-anchor the 15 scalar invariants so LICM can't
// hoist derived values (FETCH 23GB -> 12MB when applied). Do not remove.
#define ANCHOR() asm volatile("" \
    : "+v"(cww), "+v"(sww), "+v"(coo), "+v"(soo), "+v"(cll), "+v"(sll), \
      "+v"(c0a), "+v"(s0a), "+v"(ta), "+v"(tswv), "+v"(s1bv), "+v"(t5v), \
      "+v"(s2kv), "+v"(s2cv), "+v"(mskv))

__global__ __launch_bounds__(256) void ista_fft_kernel(
    const float* __restrict__ x, const int* __restrict__ idxs,
    float* __restrict__ out)
{
    __shared__ __align__(16) cf wk[2048];   // 16 KB, swizzled slot space
    __shared__ __align__(16) cf gp[2048];   // 16 KB: gp[k] = (u_s[k], u_{s+1}[k])
    // total EXACTLY 32768 B -> 5 resident blocks/CU (mbm aliased into wk)

    const int t = threadIdx.x;
    int ta   = t;
    int t5v  = t >> 5;
    int s1bv = t & 31;
    int s2kv = t & 3;
    int s2cv = (t >> 2) & 7;
    int tswv = SWZ(t);

    // measurement bitmask built in wk's storage (dead until first zero-fill)
    unsigned* mbmp = (unsigned*)&wk[0];     // 64 u32 = 256 B
    if (t < 64) mbmp[t] = 0u;
    __syncthreads();

    const int mi0 = load_idx(idxs, t), mi1 = load_idx(idxs, t + 256);
    const int yd0 = (mi0 & 1) ? (2047 - (mi0 >> 1)) : (mi0 >> 1);
    const int yd1 = (mi1 & 1) ? (2047 - (mi1 >> 1)) : (mi1 >> 1);
    const int pm0 = pinv(yd0), pm1 = pinv(yd1);
    atomicOr(&mbmp[pm0 >> 5], 1u << (pm0 & 31));
    atomicOr(&mbmp[pm1 >> 5], 1u << (pm1 & 31));
    const int sl0 = SWZ(pm0), sl1 = SWZ(pm1);
    __syncthreads();
    unsigned mskv = (mbmp[t >> 2] >> ((t & 3) * 8)) & 0xffu;  // to register
    __syncthreads();   // all mskv reads done before wk is zero-filled

    // the ONLY trig state: generators + half-angle pair (8 floats)
    float s0a, c0a; sincosf(PIF * (float)t * (1.f / 4096.f), &s0a, &c0a);
    float sww, cww; sincosf(2.f * PIF * (float)t    * (1.f / 2048.f), &sww, &cww);
    float soo, coo; sincosf(2.f * PIF * (float)s1bv * (1.f / 256.f),  &soo, &coo);
    float sll, cll; sincosf(2.f * PIF * (float)s2kv * (1.f / 32.f),   &sll, &cll);

    const int r0 = 2 * blockIdx.x, r1 = r0 + 1;   // one pair per block
    ANCHOR();

    // ---- init: wk = scatter(100*(x0 + i*x1)) in swizzled slot space ----
#pragma unroll
    for (int j = 0; j < 8; ++j) wk[t + 256 * j] = mk(0.f, 0.f);
    __syncthreads();
    wk[sl0] = mk(100.f * x[(size_t)r0 * 2048 + mi0],
                 100.f * x[(size_t)r1 * 2048 + mi0]);
    wk[sl1] = mk(100.f * x[(size_t)r0 * 2048 + mi1],
                 100.f * x[(size_t)r1 * 2048 + mi1]);
    __syncthreads();                          // scatter is cross-wave
    QUADT0(0) QUADT0(1)                       // T0 (input pre-masked)
    // T0 -> T1 -> T2 are wave-local: no barriers (r9-verified)
    DITMID(A2j, cll, sll);                    // T1
    DITMID(A1j, coo, soo);                    // T2
    __syncthreads();                          // T2 -> TAILP A0j is cross-wave
    TAILP(true);           __syncthreads();   // gp = (u0_s, u0_{s+1})

    // ---- 99 iterations (per pair) ----
#pragma unroll 1
    for (int it = 0; it < 99; ++it) {
        ANCHOR();
        HEADP(false);          __syncthreads();   // S0 store (A0j) cross-wave
        DIFMID(A1j, coo, soo);                    // S1   } wave-local chain:
        DIFMID(A2j, cll, sll);                    // S2   } each wave touches
        QUADMASK(0) QUADMASK(1)                   // S3+mask+T0 } only its own
        DITMID(A2j, cll, sll);                    // T1   } 512-slot range
        DITMID(A1j, coo, soo);                    // T2   }
        __syncthreads();                          // T2 -> TAILP A0j cross-wave
        TAILP(false);          __syncthreads();   // split + gp update
    }

    // ---- final: out_s = 0.01*Re, out_{s+1} = 0.01*Im of IDCT(F') ----
    ANCHOR();
    HEADP(true);           __syncthreads();
    DIFMID(A1j, coo, soo);                        // wave-local
    DIFMID(A2j, cll, sll);                        // wave-local
    {   // S3 into regs (wave-local reads), then scatter to x-order through wk
        cf e0, e1, e2, e3, e4, e5, e6, e7;
        {
            const int a_ = SWZ(8 * ta);
            float4 lo_ = *(const float4*)(&wk[a_]);
            float4 hi_ = *(const float4*)(&wk[a_ + 2]);
            e0 = mk(lo_.x, lo_.y); e1 = mk(lo_.z, lo_.w);
            e2 = mk(hi_.x, hi_.y); e3 = mk(hi_.z, hi_.w);
            dft4r<1>(e0, e1, e2, e3);
        }
        {
            const int a_ = SWZ(8 * ta + 4);
            float4 lo_ = *(const float4*)(&wk[a_]);
            float4 hi_ = *(const float4*)(&wk[a_ + 2]);
            e4 = mk(lo_.x, lo_.y); e5 = mk(lo_.z, lo_.w);
            e6 = mk(hi_.x, hi_.y); e7 = mk(hi_.z, hi_.w);
            dft4r<1>(e4, e5, e6, e7);
        }
        __syncthreads();   // all quad reads done before wk is repurposed
#define FSC(e, off) { \
        const int m_ = permf(8 * ta + (off)); \
        const int i_ = (m_ < 1024) ? (m_ << 1) : (4095 - (m_ << 1)); \
        wk[i_] = mk(0.01f * e.x, 0.01f * e.y); }
        FSC(e0, 0) FSC(e1, 1) FSC(e2, 2) FSC(e3, 3)
        FSC(e4, 4) FSC(e5, 5) FSC(e6, 6) FSC(e7, 7)
#undef FSC
        __syncthreads();
#pragma unroll
        for (int j = 0; j < 8; ++j) {
            const cf o_ = wk[t + 256 * j];
            out[(size_t)r0 * 2048 + t + 256 * j] = o_.x;
            out[(size_t)r1 * 2048 + t + 256 * j] = o_.y;
        }
    }
}

extern "C" void kernel_launch(void* const* d_in, const int* in_sizes, int n_in,
                              void* d_out, int out_size, void* d_ws, size_t ws_size,
                              hipStream_t stream) {
    (void)in_sizes; (void)n_in; (void)out_size; (void)d_ws; (void)ws_size;
    const float* x = (const float*)d_in[0];
    const int* idxs = (const int*)d_in[1];
    // 3072 signals = 1536 pairs, ONE pair per block (5 resident blocks/CU)
    ista_fft_kernel<<<dim3(1536), dim3(256), 0, stream>>>(x, idxs, (float*)d_out);
}